// Round 2
// baseline (3534.076 us; speedup 1.0000x reference)
//
#include <hip/hip_runtime.h>
#include <hip/hip_bf16.h>

// APPNP: h = MLP(x); 10x { h = 0.9 * (D^-1/2 (A+I) D^-1/2) h + 0.1 * h0 }
// Dataset is fp32 (NaN fingerprint in round 1 proved fp32-read-as-bf16).
// fp32 in/out; GEMMs run bf16 MFMA with inline fp32->bf16 conversion
// (propagation contraction makes bf16 GEMM error ~4e-4 << 0.0298 threshold).
//
// Pipeline per launch (all on stream, no sync, no malloc):
//   transpose+convert W1,W2 -> bf16 [n][k]
//   gemm1 (MFMA bf16 128x128): h1 = relu(X@W1+b1)   [N,256] bf16 (X cvt inline)
//   gemm2 (MFMA bf16 128x64):  H0 = h1@W2+b2        [N,64]  fp32
//   degree count -> dinv -> prefix scan -> CSR fill (src,w packed int2)
//   10x prop_step: wave-per-node, lane-per-feature (64 feats = 64 lanes)

typedef __bf16 bf16x8 __attribute__((ext_vector_type(8)));
typedef float f32x4 __attribute__((ext_vector_type(4)));

static constexpr int IN = 512, HID = 256, OUT = 64;
static constexpr int LDT = 40;  // LDS row stride in bf16 elems (80B: 16B-aligned, conflict-benign)

static __device__ __forceinline__ ushort f2bf(float f) {
  __hip_bfloat16 b = __float2bfloat16(f);
  return *reinterpret_cast<ushort*>(&b);
}

// ---------------- transpose fp32 [K][C] -> bf16 [C][K] ----------------
__global__ void transpose_f32_bf16(const float* __restrict__ in, ushort* __restrict__ out,
                                   int K, int C) {
  int idx = blockIdx.x * 256 + threadIdx.x;
  if (idx < K * C) {
    int n = idx / K, k = idx % K;
    out[idx] = f2bf(in[k * C + n]);
  }
}

// ---------------- GEMM1: h1 = relu(X @ W1 + b1) ----------------
// X [M,512] fp32 (cvt->bf16 inline), W1T [256,512] bf16, h1 [M,256] bf16. Tile 128x128x32.
__global__ __launch_bounds__(256) void gemm1(const float* __restrict__ X,
                                             const ushort* __restrict__ W1T,
                                             const float* __restrict__ b1,
                                             ushort* __restrict__ h1, int M) {
  __shared__ __align__(16) ushort As[128 * LDT];
  __shared__ __align__(16) ushort Bs[128 * LDT];
  const int tid = threadIdx.x;
  const int m0 = blockIdx.x * 128;
  const int n0 = blockIdx.y * 128;
  const int lane = tid & 63, w = tid >> 6;
  const int wr = w >> 1, wc = w & 1;
  const int lm = lane & 15, lq = lane >> 4;
  const int cB = tid & 3, rB = tid >> 2;   // B staging: 16B bf16 chunks
  const int cA = tid & 7, rA = tid >> 3;   // A staging: float4 -> 4 bf16 (8B)

  f32x4 acc[4][4] = {};

  for (int k0 = 0; k0 < IN; k0 += 32) {
    // A: 128 rows x 32 f32 -> bf16. 256 thr x float4 = 32 rows/pass, 4 passes.
#pragma unroll
    for (int rr = 0; rr < 4; ++rr) {
      int m = rA + rr * 32;
      int gm = m0 + m; gm = gm < M ? gm : M - 1;
      float4 f = *reinterpret_cast<const float4*>(&X[(size_t)gm * IN + k0 + cA * 4]);
      ushort4 cv;
      cv.x = f2bf(f.x); cv.y = f2bf(f.y); cv.z = f2bf(f.z); cv.w = f2bf(f.w);
      *reinterpret_cast<ushort4*>(&As[m * LDT + cA * 4]) = cv;
    }
    // B: 128 rows x 32 bf16, int4 chunks. 64 rows/pass, 2 passes.
#pragma unroll
    for (int rr = 0; rr < 2; ++rr) {
      int n = rB + rr * 64;
      *reinterpret_cast<int4*>(&Bs[n * LDT + cB * 8]) =
          *reinterpret_cast<const int4*>(&W1T[(size_t)(n0 + n) * IN + k0 + cB * 8]);
    }
    __syncthreads();
    bf16x8 af[4], bq[4];
#pragma unroll
    for (int mi = 0; mi < 4; ++mi)
      af[mi] = *reinterpret_cast<const bf16x8*>(&As[(wr * 64 + mi * 16 + lm) * LDT + lq * 8]);
#pragma unroll
    for (int ni = 0; ni < 4; ++ni)
      bq[ni] = *reinterpret_cast<const bf16x8*>(&Bs[(wc * 64 + ni * 16 + lm) * LDT + lq * 8]);
#pragma unroll
    for (int mi = 0; mi < 4; ++mi)
#pragma unroll
      for (int ni = 0; ni < 4; ++ni)
        acc[mi][ni] = __builtin_amdgcn_mfma_f32_16x16x32_bf16(af[mi], bq[ni], acc[mi][ni], 0, 0, 0);
    __syncthreads();
  }

#pragma unroll
  for (int ni = 0; ni < 4; ++ni) {
    int col = n0 + wc * 64 + ni * 16 + lm;
    float bias = b1[col];
#pragma unroll
    for (int mi = 0; mi < 4; ++mi) {
#pragma unroll
      for (int rg = 0; rg < 4; ++rg) {
        int row = m0 + wr * 64 + mi * 16 + lq * 4 + rg;
        if (row < M) {
          float v = acc[mi][ni][rg] + bias;
          v = v > 0.f ? v : 0.f;
          h1[(size_t)row * HID + col] = f2bf(v);
        }
      }
    }
  }
}

// ---------------- GEMM2: H0 = h1 @ W2 + b2, fp32 out ----------------
// h1 [M,256] bf16, W2T [64,256] bf16, H0 [M,64] fp32. Tile 128x64x32, 4 waves x (32x64).
__global__ __launch_bounds__(256) void gemm2(const ushort* __restrict__ h1,
                                             const ushort* __restrict__ W2T,
                                             const float* __restrict__ b2,
                                             float* __restrict__ H0, int M) {
  __shared__ __align__(16) ushort As[128 * LDT];
  __shared__ __align__(16) ushort Bs[64 * LDT];
  const int tid = threadIdx.x;
  const int m0 = blockIdx.x * 128;
  const int lane = tid & 63, w = tid >> 6;
  const int lm = lane & 15, lq = lane >> 4;
  const int c = tid & 3, r = tid >> 2;

  f32x4 acc[2][4] = {};

  for (int k0 = 0; k0 < HID; k0 += 32) {
#pragma unroll
    for (int rr = 0; rr < 2; ++rr) {
      int m = r + rr * 64;
      int gm = m0 + m; gm = gm < M ? gm : M - 1;
      *reinterpret_cast<int4*>(&As[m * LDT + c * 8]) =
          *reinterpret_cast<const int4*>(&h1[(size_t)gm * HID + k0 + c * 8]);
    }
    *reinterpret_cast<int4*>(&Bs[r * LDT + c * 8]) =
        *reinterpret_cast<const int4*>(&W2T[(size_t)r * HID + k0 + c * 8]);
    __syncthreads();
    bf16x8 af[2], bq[4];
#pragma unroll
    for (int mi = 0; mi < 2; ++mi)
      af[mi] = *reinterpret_cast<const bf16x8*>(&As[(w * 32 + mi * 16 + lm) * LDT + lq * 8]);
#pragma unroll
    for (int ni = 0; ni < 4; ++ni)
      bq[ni] = *reinterpret_cast<const bf16x8*>(&Bs[(ni * 16 + lm) * LDT + lq * 8]);
#pragma unroll
    for (int mi = 0; mi < 2; ++mi)
#pragma unroll
      for (int ni = 0; ni < 4; ++ni)
        acc[mi][ni] = __builtin_amdgcn_mfma_f32_16x16x32_bf16(af[mi], bq[ni], acc[mi][ni], 0, 0, 0);
    __syncthreads();
  }

#pragma unroll
  for (int ni = 0; ni < 4; ++ni) {
    int col = ni * 16 + lm;
    float bias = b2[col];
#pragma unroll
    for (int mi = 0; mi < 2; ++mi) {
#pragma unroll
      for (int rg = 0; rg < 4; ++rg) {
        int row = m0 + w * 32 + mi * 16 + lq * 4 + rg;
        if (row < M) H0[(size_t)row * OUT + col] = acc[mi][ni][rg] + bias;
      }
    }
  }
}

// ---------------- degree / dinv / scan / CSR ----------------
__global__ void count_deg(const int* __restrict__ ei, int* __restrict__ cnt, int E) {
  int e = blockIdx.x * 256 + threadIdx.x;
  if (e < E) atomicAdd(&cnt[ei[E + e]], 1);
}

__global__ void calc_dinv(const int* __restrict__ cnt, float* __restrict__ dinv, int n) {
  int v = blockIdx.x * 256 + threadIdx.x;
  if (v < n) dinv[v] = rsqrtf((float)cnt[v] + 1.0f);  // +1: self-loop
}

// single-block exclusive scan of cnt[n] -> offs[n+1], cursor[n]; 4 elems/thread/iter
__global__ __launch_bounds__(1024) void scan_kernel(const int* __restrict__ cnt,
                                                    int* __restrict__ offs,
                                                    int* __restrict__ cursor, int n) {
  __shared__ int wsum[16];
  __shared__ int woff[16];
  __shared__ int carry_s;
  const int tid = threadIdx.x;
  const int lane = tid & 63, wid = tid >> 6;
  if (tid == 0) carry_s = 0;
  __syncthreads();
  for (int base = 0; base < n; base += 4096) {
    int i0 = base + tid * 4;
    int x[4];
#pragma unroll
    for (int j = 0; j < 4; ++j) x[j] = (i0 + j < n) ? cnt[i0 + j] : 0;
    int tsum = x[0] + x[1] + x[2] + x[3];
    int val = tsum;
#pragma unroll
    for (int d = 1; d < 64; d <<= 1) {
      int t = __shfl_up(val, d, 64);
      if (lane >= d) val += t;
    }
    if (lane == 63) wsum[wid] = val;
    __syncthreads();
    if (wid == 0) {
      int s = (lane < 16) ? wsum[lane] : 0;
      int sv = s;
#pragma unroll
      for (int d = 1; d < 16; d <<= 1) {
        int t = __shfl_up(sv, d, 64);
        if (lane >= d) sv += t;
      }
      if (lane < 16) woff[lane] = sv - s;
    }
    __syncthreads();
    int excl = carry_s + woff[wid] + (val - tsum);
#pragma unroll
    for (int j = 0; j < 4; ++j) {
      if (i0 + j < n) { offs[i0 + j] = excl; cursor[i0 + j] = excl; }
      excl += x[j];
    }
    __syncthreads();
    if (tid == 1023) carry_s = excl;  // carry + woff[15] + inclusive(wave15) = chunk total
    __syncthreads();
  }
  if (tid == 0) offs[n] = carry_s;
}

__global__ void fill_csr(const int* __restrict__ ei, int* __restrict__ cursor,
                         const float* __restrict__ dinv, int2* __restrict__ csr, int E) {
  int e = blockIdx.x * 256 + threadIdx.x;
  if (e < E) {
    int s = ei[e], d = ei[E + e];
    int p = atomicAdd(&cursor[d], 1);
    csr[p] = make_int2(s, __float_as_int(dinv[s] * dinv[d]));
  }
}

// ---------------- propagation: one wave per node, one lane per feature ----------------
__global__ __launch_bounds__(256) void prop_step(const float* __restrict__ hin,
                                                 float* __restrict__ hout,
                                                 const float* __restrict__ h0,
                                                 const int* __restrict__ offs,
                                                 const int2* __restrict__ csr,
                                                 const float* __restrict__ dinv, int n) {
  int gw = (blockIdx.x * 256 + threadIdx.x) >> 6;
  int lane = threadIdx.x & 63;
  if (gw >= n) return;
  float dv = dinv[gw];
  float acc = hin[(size_t)gw * OUT + lane] * dv * dv;  // self loop
  int e0 = offs[gw], e1 = offs[gw + 1];
  for (int e = e0; e < e1; ++e) {
    int2 sw = csr[e];
    acc += __int_as_float(sw.y) * hin[(size_t)sw.x * OUT + lane];
  }
  hout[(size_t)gw * OUT + lane] = 0.9f * acc + 0.1f * h0[(size_t)gw * OUT + lane];
}

extern "C" void kernel_launch(void* const* d_in, const int* in_sizes, int n_in,
                              void* d_out, int out_size, void* d_ws, size_t ws_size,
                              hipStream_t stream) {
  const float* X  = (const float*)d_in[0];  // [N,512] f32
  const int*   EI = (const int*)d_in[1];    // [2,E] int32
  const float* W1 = (const float*)d_in[2];  // [512,256] f32
  const float* b1 = (const float*)d_in[3];  // [256] f32
  const float* W2 = (const float*)d_in[4];  // [256,64] f32
  const float* b2 = (const float*)d_in[5];  // [64] f32
  float* out = (float*)d_out;               // [N,64] f32

  const int N = in_sizes[0] / IN;  // 100000
  const int E = in_sizes[1] / 2;   // 3200000

  char* ws = (char*)d_ws;
  size_t o = 0;
  auto alloc = [&](size_t b) {
    char* p = ws + o;
    o = (o + b + 255) & ~(size_t)255;
    return p;
  };
  float*  H0   = (float*)alloc((size_t)N * OUT * 4);
  float*  hA   = (float*)alloc((size_t)N * OUT * 4);
  float*  hB   = (float*)alloc((size_t)N * OUT * 4);
  ushort* h1   = (ushort*)alloc((size_t)N * HID * 2);
  ushort* W1T  = (ushort*)alloc((size_t)IN * HID * 2);
  ushort* W2T  = (ushort*)alloc((size_t)HID * OUT * 2);
  int*    cnt  = (int*)alloc((size_t)N * 4);
  int*    offs = (int*)alloc((size_t)(N + 1) * 4);
  int*    curs = (int*)alloc((size_t)N * 4);
  float*  dinv = (float*)alloc((size_t)N * 4);
  int2*   csr  = (int2*)alloc((size_t)E * 8);
  (void)ws_size; (void)n_in; (void)out_size;  // ~155 MB total

  transpose_f32_bf16<<<(IN * HID + 255) / 256, 256, 0, stream>>>(W1, W1T, IN, HID);
  transpose_f32_bf16<<<(HID * OUT + 255) / 256, 256, 0, stream>>>(W2, W2T, HID, OUT);

  gemm1<<<dim3((N + 127) / 128, HID / 128), 256, 0, stream>>>(X, W1T, b1, h1, N);
  gemm2<<<(N + 127) / 128, 256, 0, stream>>>(h1, W2T, b2, H0, N);

  hipMemsetAsync(cnt, 0, (size_t)N * 4, stream);
  count_deg<<<(E + 255) / 256, 256, 0, stream>>>(EI, cnt, E);
  calc_dinv<<<(N + 255) / 256, 256, 0, stream>>>(cnt, dinv, N);
  scan_kernel<<<1, 1024, 0, stream>>>(cnt, offs, curs, N);
  fill_csr<<<(E + 255) / 256, 256, 0, stream>>>(EI, curs, dinv, csr, E);

  const int pgrid = (N * OUT + 255) / 256;  // one wave per node
  prop_step<<<pgrid, 256, 0, stream>>>(H0, hA, H0, offs, csr, dinv, N);
  for (int i = 0; i < 4; ++i) {
    prop_step<<<pgrid, 256, 0, stream>>>(hA, hB, H0, offs, csr, dinv, N);
    prop_step<<<pgrid, 256, 0, stream>>>(hB, hA, H0, offs, csr, dinv, N);
  }
  prop_step<<<pgrid, 256, 0, stream>>>(hA, out, H0, offs, csr, dinv, N);
}

// Round 3
// 1843.381 us; speedup vs baseline: 1.9172x; 1.9172x over previous
//
#include <hip/hip_runtime.h>
#include <hip/hip_bf16.h>

// APPNP: h = MLP(x); 10x { h = 0.9 * (D^-1/2 (A+I) D^-1/2) h + 0.1 * h0 }
// fp32 in/out; GEMMs run bf16 MFMA with inline fp32->bf16 conversion.
// R3: prop_step restructured for memory-level parallelism —
//     per-lane CSR batch fetch + shfl broadcast + 8-way unrolled gathers
//     (8 independent 256B gathers in flight per wave vs ~1 before).

typedef __bf16 bf16x8 __attribute__((ext_vector_type(8)));
typedef float f32x4 __attribute__((ext_vector_type(4)));

static constexpr int IN = 512, HID = 256, OUT = 64;
static constexpr int LDT = 40;  // LDS row stride in bf16 elems (80B: 16B-aligned, conflict-benign)

static __device__ __forceinline__ ushort f2bf(float f) {
  __hip_bfloat16 b = __float2bfloat16(f);
  return *reinterpret_cast<ushort*>(&b);
}

// ---------------- transpose fp32 [K][C] -> bf16 [C][K] ----------------
__global__ void transpose_f32_bf16(const float* __restrict__ in, ushort* __restrict__ out,
                                   int K, int C) {
  int idx = blockIdx.x * 256 + threadIdx.x;
  if (idx < K * C) {
    int n = idx / K, k = idx % K;
    out[idx] = f2bf(in[k * C + n]);
  }
}

// ---------------- GEMM1: h1 = relu(X @ W1 + b1) ----------------
// X [M,512] fp32 (cvt->bf16 inline), W1T [256,512] bf16, h1 [M,256] bf16. Tile 128x128x32.
__global__ __launch_bounds__(256) void gemm1(const float* __restrict__ X,
                                             const ushort* __restrict__ W1T,
                                             const float* __restrict__ b1,
                                             ushort* __restrict__ h1, int M) {
  __shared__ __align__(16) ushort As[128 * LDT];
  __shared__ __align__(16) ushort Bs[128 * LDT];
  const int tid = threadIdx.x;
  const int m0 = blockIdx.x * 128;
  const int n0 = blockIdx.y * 128;
  const int lane = tid & 63, w = tid >> 6;
  const int wr = w >> 1, wc = w & 1;
  const int lm = lane & 15, lq = lane >> 4;
  const int cB = tid & 3, rB = tid >> 2;   // B staging: 16B bf16 chunks
  const int cA = tid & 7, rA = tid >> 3;   // A staging: float4 -> 4 bf16 (8B)

  f32x4 acc[4][4] = {};

  for (int k0 = 0; k0 < IN; k0 += 32) {
    // A: 128 rows x 32 f32 -> bf16. 256 thr x float4 = 32 rows/pass, 4 passes.
#pragma unroll
    for (int rr = 0; rr < 4; ++rr) {
      int m = rA + rr * 32;
      int gm = m0 + m; gm = gm < M ? gm : M - 1;
      float4 f = *reinterpret_cast<const float4*>(&X[(size_t)gm * IN + k0 + cA * 4]);
      ushort4 cv;
      cv.x = f2bf(f.x); cv.y = f2bf(f.y); cv.z = f2bf(f.z); cv.w = f2bf(f.w);
      *reinterpret_cast<ushort4*>(&As[m * LDT + cA * 4]) = cv;
    }
    // B: 128 rows x 32 bf16, int4 chunks. 64 rows/pass, 2 passes.
#pragma unroll
    for (int rr = 0; rr < 2; ++rr) {
      int n = rB + rr * 64;
      *reinterpret_cast<int4*>(&Bs[n * LDT + cB * 8]) =
          *reinterpret_cast<const int4*>(&W1T[(size_t)(n0 + n) * IN + k0 + cB * 8]);
    }
    __syncthreads();
    bf16x8 af[4], bq[4];
#pragma unroll
    for (int mi = 0; mi < 4; ++mi)
      af[mi] = *reinterpret_cast<const bf16x8*>(&As[(wr * 64 + mi * 16 + lm) * LDT + lq * 8]);
#pragma unroll
    for (int ni = 0; ni < 4; ++ni)
      bq[ni] = *reinterpret_cast<const bf16x8*>(&Bs[(wc * 64 + ni * 16 + lm) * LDT + lq * 8]);
#pragma unroll
    for (int mi = 0; mi < 4; ++mi)
#pragma unroll
      for (int ni = 0; ni < 4; ++ni)
        acc[mi][ni] = __builtin_amdgcn_mfma_f32_16x16x32_bf16(af[mi], bq[ni], acc[mi][ni], 0, 0, 0);
    __syncthreads();
  }

#pragma unroll
  for (int ni = 0; ni < 4; ++ni) {
    int col = n0 + wc * 64 + ni * 16 + lm;
    float bias = b1[col];
#pragma unroll
    for (int mi = 0; mi < 4; ++mi) {
#pragma unroll
      for (int rg = 0; rg < 4; ++rg) {
        int row = m0 + wr * 64 + mi * 16 + lq * 4 + rg;
        if (row < M) {
          float v = acc[mi][ni][rg] + bias;
          v = v > 0.f ? v : 0.f;
          h1[(size_t)row * HID + col] = f2bf(v);
        }
      }
    }
  }
}

// ---------------- GEMM2: H0 = h1 @ W2 + b2, fp32 out ----------------
// h1 [M,256] bf16, W2T [64,256] bf16, H0 [M,64] fp32. Tile 128x64x32, 4 waves x (32x64).
__global__ __launch_bounds__(256) void gemm2(const ushort* __restrict__ h1,
                                             const ushort* __restrict__ W2T,
                                             const float* __restrict__ b2,
                                             float* __restrict__ H0, int M) {
  __shared__ __align__(16) ushort As[128 * LDT];
  __shared__ __align__(16) ushort Bs[64 * LDT];
  const int tid = threadIdx.x;
  const int m0 = blockIdx.x * 128;
  const int lane = tid & 63, w = tid >> 6;
  const int lm = lane & 15, lq = lane >> 4;
  const int c = tid & 3, r = tid >> 2;

  f32x4 acc[2][4] = {};

  for (int k0 = 0; k0 < HID; k0 += 32) {
#pragma unroll
    for (int rr = 0; rr < 2; ++rr) {
      int m = r + rr * 64;
      int gm = m0 + m; gm = gm < M ? gm : M - 1;
      *reinterpret_cast<int4*>(&As[m * LDT + c * 8]) =
          *reinterpret_cast<const int4*>(&h1[(size_t)gm * HID + k0 + c * 8]);
    }
    *reinterpret_cast<int4*>(&Bs[r * LDT + c * 8]) =
        *reinterpret_cast<const int4*>(&W2T[(size_t)r * HID + k0 + c * 8]);
    __syncthreads();
    bf16x8 af[2], bq[4];
#pragma unroll
    for (int mi = 0; mi < 2; ++mi)
      af[mi] = *reinterpret_cast<const bf16x8*>(&As[(w * 32 + mi * 16 + lm) * LDT + lq * 8]);
#pragma unroll
    for (int ni = 0; ni < 4; ++ni)
      bq[ni] = *reinterpret_cast<const bf16x8*>(&Bs[(ni * 16 + lm) * LDT + lq * 8]);
#pragma unroll
    for (int mi = 0; mi < 2; ++mi)
#pragma unroll
      for (int ni = 0; ni < 4; ++ni)
        acc[mi][ni] = __builtin_amdgcn_mfma_f32_16x16x32_bf16(af[mi], bq[ni], acc[mi][ni], 0, 0, 0);
    __syncthreads();
  }

#pragma unroll
  for (int ni = 0; ni < 4; ++ni) {
    int col = ni * 16 + lm;
    float bias = b2[col];
#pragma unroll
    for (int mi = 0; mi < 2; ++mi) {
#pragma unroll
      for (int rg = 0; rg < 4; ++rg) {
        int row = m0 + w * 32 + mi * 16 + lq * 4 + rg;
        if (row < M) H0[(size_t)row * OUT + col] = acc[mi][ni][rg] + bias;
      }
    }
  }
}

// ---------------- degree / dinv / scan / CSR ----------------
__global__ void count_deg(const int* __restrict__ ei, int* __restrict__ cnt, int E) {
  int e = blockIdx.x * 256 + threadIdx.x;
  if (e < E) atomicAdd(&cnt[ei[E + e]], 1);
}

__global__ void calc_dinv(const int* __restrict__ cnt, float* __restrict__ dinv, int n) {
  int v = blockIdx.x * 256 + threadIdx.x;
  if (v < n) dinv[v] = rsqrtf((float)cnt[v] + 1.0f);  // +1: self-loop
}

// single-block exclusive scan of cnt[n] -> offs[n+1], cursor[n]; 4 elems/thread/iter
__global__ __launch_bounds__(1024) void scan_kernel(const int* __restrict__ cnt,
                                                    int* __restrict__ offs,
                                                    int* __restrict__ cursor, int n) {
  __shared__ int wsum[16];
  __shared__ int woff[16];
  __shared__ int carry_s;
  const int tid = threadIdx.x;
  const int lane = tid & 63, wid = tid >> 6;
  if (tid == 0) carry_s = 0;
  __syncthreads();
  for (int base = 0; base < n; base += 4096) {
    int i0 = base + tid * 4;
    int x[4];
#pragma unroll
    for (int j = 0; j < 4; ++j) x[j] = (i0 + j < n) ? cnt[i0 + j] : 0;
    int tsum = x[0] + x[1] + x[2] + x[3];
    int val = tsum;
#pragma unroll
    for (int d = 1; d < 64; d <<= 1) {
      int t = __shfl_up(val, d, 64);
      if (lane >= d) val += t;
    }
    if (lane == 63) wsum[wid] = val;
    __syncthreads();
    if (wid == 0) {
      int s = (lane < 16) ? wsum[lane] : 0;
      int sv = s;
#pragma unroll
      for (int d = 1; d < 16; d <<= 1) {
        int t = __shfl_up(sv, d, 64);
        if (lane >= d) sv += t;
      }
      if (lane < 16) woff[lane] = sv - s;
    }
    __syncthreads();
    int excl = carry_s + woff[wid] + (val - tsum);
#pragma unroll
    for (int j = 0; j < 4; ++j) {
      if (i0 + j < n) { offs[i0 + j] = excl; cursor[i0 + j] = excl; }
      excl += x[j];
    }
    __syncthreads();
    if (tid == 1023) carry_s = excl;
    __syncthreads();
  }
  if (tid == 0) offs[n] = carry_s;
}

__global__ void fill_csr(const int* __restrict__ ei, int* __restrict__ cursor,
                         const float* __restrict__ dinv, int2* __restrict__ csr, int E) {
  int e = blockIdx.x * 256 + threadIdx.x;
  if (e < E) {
    int s = ei[e], d = ei[E + e];
    int p = atomicAdd(&cursor[d], 1);
    csr[p] = make_int2(s, __float_as_int(dinv[s] * dinv[d]));
  }
}

// ---------------- propagation: one wave per node, one lane per feature ----------------
// MLP restructure: lane l fetches csr[base+l] (one coalesced 512B load per 64 edges),
// src/w broadcast via shfl; gather loop unrolled x8 with 8 independent accumulators
// so 8 x 256B gathers are in flight per wave simultaneously.
__global__ __launch_bounds__(256) void prop_step(const float* __restrict__ hin,
                                                 float* __restrict__ hout,
                                                 const float* __restrict__ h0,
                                                 const int* __restrict__ offs,
                                                 const int2* __restrict__ csr,
                                                 const float* __restrict__ dinv, int n) {
  int gw = (blockIdx.x * 256 + threadIdx.x) >> 6;
  int lane = threadIdx.x & 63;
  if (gw >= n) return;
  float dv = dinv[gw];
  float a0 = hin[(size_t)gw * OUT + lane] * dv * dv;  // self loop
  float a1 = 0.f, a2 = 0.f, a3 = 0.f, a4 = 0.f, a5 = 0.f, a6 = 0.f, a7 = 0.f;
  int e0 = offs[gw], e1 = offs[gw + 1];
  for (int base = e0; base < e1; base += 64) {
    int rem = e1 - base;
    // padded lanes: w=0, src=0 (row 0 is a valid address; contribution is 0)
    int2 my = (lane < rem) ? csr[base + lane] : make_int2(0, 0);
    int cnt = rem < 64 ? rem : 64;
    int cnt8 = (cnt + 7) & ~7;
    for (int j = 0; j < cnt8; j += 8) {
      int s0 = __shfl(my.x, j + 0), s1 = __shfl(my.x, j + 1);
      int s2 = __shfl(my.x, j + 2), s3 = __shfl(my.x, j + 3);
      int s4 = __shfl(my.x, j + 4), s5 = __shfl(my.x, j + 5);
      int s6 = __shfl(my.x, j + 6), s7 = __shfl(my.x, j + 7);
      float w0 = __int_as_float(__shfl(my.y, j + 0));
      float w1 = __int_as_float(__shfl(my.y, j + 1));
      float w2 = __int_as_float(__shfl(my.y, j + 2));
      float w3 = __int_as_float(__shfl(my.y, j + 3));
      float w4 = __int_as_float(__shfl(my.y, j + 4));
      float w5 = __int_as_float(__shfl(my.y, j + 5));
      float w6 = __int_as_float(__shfl(my.y, j + 6));
      float w7 = __int_as_float(__shfl(my.y, j + 7));
      float v0 = hin[(size_t)s0 * OUT + lane];
      float v1 = hin[(size_t)s1 * OUT + lane];
      float v2 = hin[(size_t)s2 * OUT + lane];
      float v3 = hin[(size_t)s3 * OUT + lane];
      float v4 = hin[(size_t)s4 * OUT + lane];
      float v5 = hin[(size_t)s5 * OUT + lane];
      float v6 = hin[(size_t)s6 * OUT + lane];
      float v7 = hin[(size_t)s7 * OUT + lane];
      a0 = fmaf(w0, v0, a0); a1 = fmaf(w1, v1, a1);
      a2 = fmaf(w2, v2, a2); a3 = fmaf(w3, v3, a3);
      a4 = fmaf(w4, v4, a4); a5 = fmaf(w5, v5, a5);
      a6 = fmaf(w6, v6, a6); a7 = fmaf(w7, v7, a7);
    }
  }
  float acc = ((a0 + a1) + (a2 + a3)) + ((a4 + a5) + (a6 + a7));
  hout[(size_t)gw * OUT + lane] = 0.9f * acc + 0.1f * h0[(size_t)gw * OUT + lane];
}

extern "C" void kernel_launch(void* const* d_in, const int* in_sizes, int n_in,
                              void* d_out, int out_size, void* d_ws, size_t ws_size,
                              hipStream_t stream) {
  const float* X  = (const float*)d_in[0];  // [N,512] f32
  const int*   EI = (const int*)d_in[1];    // [2,E] int32
  const float* W1 = (const float*)d_in[2];  // [512,256] f32
  const float* b1 = (const float*)d_in[3];  // [256] f32
  const float* W2 = (const float*)d_in[4];  // [256,64] f32
  const float* b2 = (const float*)d_in[5];  // [64] f32
  float* out = (float*)d_out;               // [N,64] f32

  const int N = in_sizes[0] / IN;  // 100000
  const int E = in_sizes[1] / 2;   // 3200000

  char* ws = (char*)d_ws;
  size_t o = 0;
  auto alloc = [&](size_t b) {
    char* p = ws + o;
    o = (o + b + 255) & ~(size_t)255;
    return p;
  };
  float*  H0   = (float*)alloc((size_t)N * OUT * 4);
  float*  hA   = (float*)alloc((size_t)N * OUT * 4);
  float*  hB   = (float*)alloc((size_t)N * OUT * 4);
  ushort* h1   = (ushort*)alloc((size_t)N * HID * 2);
  ushort* W1T  = (ushort*)alloc((size_t)IN * HID * 2);
  ushort* W2T  = (ushort*)alloc((size_t)HID * OUT * 2);
  int*    cnt  = (int*)alloc((size_t)N * 4);
  int*    offs = (int*)alloc((size_t)(N + 1) * 4);
  int*    curs = (int*)alloc((size_t)N * 4);
  float*  dinv = (float*)alloc((size_t)N * 4);
  int2*   csr  = (int2*)alloc((size_t)E * 8);
  (void)ws_size; (void)n_in; (void)out_size;  // ~155 MB total

  transpose_f32_bf16<<<(IN * HID + 255) / 256, 256, 0, stream>>>(W1, W1T, IN, HID);
  transpose_f32_bf16<<<(HID * OUT + 255) / 256, 256, 0, stream>>>(W2, W2T, HID, OUT);

  gemm1<<<dim3((N + 127) / 128, HID / 128), 256, 0, stream>>>(X, W1T, b1, h1, N);
  gemm2<<<(N + 127) / 128, 256, 0, stream>>>(h1, W2T, b2, H0, N);

  hipMemsetAsync(cnt, 0, (size_t)N * 4, stream);
  count_deg<<<(E + 255) / 256, 256, 0, stream>>>(EI, cnt, E);
  calc_dinv<<<(N + 255) / 256, 256, 0, stream>>>(cnt, dinv, N);
  scan_kernel<<<1, 1024, 0, stream>>>(cnt, offs, curs, N);
  fill_csr<<<(E + 255) / 256, 256, 0, stream>>>(EI, curs, dinv, csr, E);

  const int pgrid = (N * OUT + 255) / 256;  // one wave per node
  prop_step<<<pgrid, 256, 0, stream>>>(H0, hA, H0, offs, csr, dinv, N);
  for (int i = 0; i < 4; ++i) {
    prop_step<<<pgrid, 256, 0, stream>>>(hA, hB, H0, offs, csr, dinv, N);
    prop_step<<<pgrid, 256, 0, stream>>>(hB, hA, H0, offs, csr, dinv, N);
  }
  prop_step<<<pgrid, 256, 0, stream>>>(hA, out, H0, offs, csr, dinv, N);
}

// Round 4
// 1386.154 us; speedup vs baseline: 2.5496x; 1.3299x over previous
//
#include <hip/hip_runtime.h>
#include <hip/hip_bf16.h>
#include <hip/hip_fp16.h>

// APPNP: h = MLP(x); 10x { h = 0.9 * (D^-1/2 (A+I) D^-1/2) h + 0.1 * h0 }
// fp32 in/out; GEMMs run bf16 MFMA with inline fp32->bf16 conversion.
// R4: byte-diet on the two line-amplified paths —
//   - h kept in fp32 (exact self/teleport) + bf16 mirror (neighbor gathers: 128B rows)
//   - CSR packed to 4B/edge: (src<<15) | fp16bits(w)  (src<2^17, w>0 so sign bit free)
//   - 16 outstanding gathers per wave (8 accumulators, reuse distance 8)

typedef __bf16 bf16x8 __attribute__((ext_vector_type(8)));
typedef float f32x4 __attribute__((ext_vector_type(4)));

static constexpr int IN = 512, HID = 256, OUT = 64;
static constexpr int LDT = 40;  // LDS row stride in bf16 elems

static __device__ __forceinline__ ushort f2bf(float f) {
  __hip_bfloat16 b = __float2bfloat16(f);
  return *reinterpret_cast<ushort*>(&b);
}
static __device__ __forceinline__ float bf2f(ushort u) {
  unsigned int x = ((unsigned int)u) << 16;
  return __uint_as_float(x);
}
// decode low-15-bit fp16 (sign=0) weight
static __device__ __forceinline__ float h15f(unsigned int u) {
  ushort hb = (ushort)(u & 0x7FFFu);
  __half h = *reinterpret_cast<__half*>(&hb);
  return __half2float(h);
}

// ---------------- transpose fp32 [K][C] -> bf16 [C][K] ----------------
__global__ void transpose_f32_bf16(const float* __restrict__ in, ushort* __restrict__ out,
                                   int K, int C) {
  int idx = blockIdx.x * 256 + threadIdx.x;
  if (idx < K * C) {
    int n = idx / K, k = idx % K;
    out[idx] = f2bf(in[k * C + n]);
  }
}

// ---------------- GEMM1: h1 = relu(X @ W1 + b1) ----------------
// X [M,512] fp32 (cvt->bf16 inline), W1T [256,512] bf16, h1 [M,256] bf16. Tile 128x128x32.
__global__ __launch_bounds__(256) void gemm1(const float* __restrict__ X,
                                             const ushort* __restrict__ W1T,
                                             const float* __restrict__ b1,
                                             ushort* __restrict__ h1, int M) {
  __shared__ __align__(16) ushort As[128 * LDT];
  __shared__ __align__(16) ushort Bs[128 * LDT];
  const int tid = threadIdx.x;
  const int m0 = blockIdx.x * 128;
  const int n0 = blockIdx.y * 128;
  const int lane = tid & 63, w = tid >> 6;
  const int wr = w >> 1, wc = w & 1;
  const int lm = lane & 15, lq = lane >> 4;
  const int cB = tid & 3, rB = tid >> 2;   // B staging: 16B bf16 chunks
  const int cA = tid & 7, rA = tid >> 3;   // A staging: float4 -> 4 bf16 (8B)

  f32x4 acc[4][4] = {};

  for (int k0 = 0; k0 < IN; k0 += 32) {
#pragma unroll
    for (int rr = 0; rr < 4; ++rr) {
      int m = rA + rr * 32;
      int gm = m0 + m; gm = gm < M ? gm : M - 1;
      float4 f = *reinterpret_cast<const float4*>(&X[(size_t)gm * IN + k0 + cA * 4]);
      ushort4 cv;
      cv.x = f2bf(f.x); cv.y = f2bf(f.y); cv.z = f2bf(f.z); cv.w = f2bf(f.w);
      *reinterpret_cast<ushort4*>(&As[m * LDT + cA * 4]) = cv;
    }
#pragma unroll
    for (int rr = 0; rr < 2; ++rr) {
      int n = rB + rr * 64;
      *reinterpret_cast<int4*>(&Bs[n * LDT + cB * 8]) =
          *reinterpret_cast<const int4*>(&W1T[(size_t)(n0 + n) * IN + k0 + cB * 8]);
    }
    __syncthreads();
    bf16x8 af[4], bq[4];
#pragma unroll
    for (int mi = 0; mi < 4; ++mi)
      af[mi] = *reinterpret_cast<const bf16x8*>(&As[(wr * 64 + mi * 16 + lm) * LDT + lq * 8]);
#pragma unroll
    for (int ni = 0; ni < 4; ++ni)
      bq[ni] = *reinterpret_cast<const bf16x8*>(&Bs[(wc * 64 + ni * 16 + lm) * LDT + lq * 8]);
#pragma unroll
    for (int mi = 0; mi < 4; ++mi)
#pragma unroll
      for (int ni = 0; ni < 4; ++ni)
        acc[mi][ni] = __builtin_amdgcn_mfma_f32_16x16x32_bf16(af[mi], bq[ni], acc[mi][ni], 0, 0, 0);
    __syncthreads();
  }

#pragma unroll
  for (int ni = 0; ni < 4; ++ni) {
    int col = n0 + wc * 64 + ni * 16 + lm;
    float bias = b1[col];
#pragma unroll
    for (int mi = 0; mi < 4; ++mi) {
#pragma unroll
      for (int rg = 0; rg < 4; ++rg) {
        int row = m0 + wr * 64 + mi * 16 + lq * 4 + rg;
        if (row < M) {
          float v = acc[mi][ni][rg] + bias;
          v = v > 0.f ? v : 0.f;
          h1[(size_t)row * HID + col] = f2bf(v);
        }
      }
    }
  }
}

// ---------------- GEMM2: H0 = h1 @ W2 + b2, fp32 + bf16 mirror out ----------------
__global__ __launch_bounds__(256) void gemm2(const ushort* __restrict__ h1,
                                             const ushort* __restrict__ W2T,
                                             const float* __restrict__ b2,
                                             float* __restrict__ H0f,
                                             ushort* __restrict__ H0b, int M) {
  __shared__ __align__(16) ushort As[128 * LDT];
  __shared__ __align__(16) ushort Bs[64 * LDT];
  const int tid = threadIdx.x;
  const int m0 = blockIdx.x * 128;
  const int lane = tid & 63, w = tid >> 6;
  const int lm = lane & 15, lq = lane >> 4;
  const int c = tid & 3, r = tid >> 2;

  f32x4 acc[2][4] = {};

  for (int k0 = 0; k0 < HID; k0 += 32) {
#pragma unroll
    for (int rr = 0; rr < 2; ++rr) {
      int m = r + rr * 64;
      int gm = m0 + m; gm = gm < M ? gm : M - 1;
      *reinterpret_cast<int4*>(&As[m * LDT + c * 8]) =
          *reinterpret_cast<const int4*>(&h1[(size_t)gm * HID + k0 + c * 8]);
    }
    *reinterpret_cast<int4*>(&Bs[r * LDT + c * 8]) =
        *reinterpret_cast<const int4*>(&W2T[(size_t)r * HID + k0 + c * 8]);
    __syncthreads();
    bf16x8 af[2], bq[4];
#pragma unroll
    for (int mi = 0; mi < 2; ++mi)
      af[mi] = *reinterpret_cast<const bf16x8*>(&As[(w * 32 + mi * 16 + lm) * LDT + lq * 8]);
#pragma unroll
    for (int ni = 0; ni < 4; ++ni)
      bq[ni] = *reinterpret_cast<const bf16x8*>(&Bs[(ni * 16 + lm) * LDT + lq * 8]);
#pragma unroll
    for (int mi = 0; mi < 2; ++mi)
#pragma unroll
      for (int ni = 0; ni < 4; ++ni)
        acc[mi][ni] = __builtin_amdgcn_mfma_f32_16x16x32_bf16(af[mi], bq[ni], acc[mi][ni], 0, 0, 0);
    __syncthreads();
  }

#pragma unroll
  for (int ni = 0; ni < 4; ++ni) {
    int col = ni * 16 + lm;
    float bias = b2[col];
#pragma unroll
    for (int mi = 0; mi < 2; ++mi) {
#pragma unroll
      for (int rg = 0; rg < 4; ++rg) {
        int row = m0 + w * 32 + mi * 16 + lq * 4 + rg;
        if (row < M) {
          float v = acc[mi][ni][rg] + bias;
          H0f[(size_t)row * OUT + col] = v;
          H0b[(size_t)row * OUT + col] = f2bf(v);
        }
      }
    }
  }
}

// ---------------- degree / dinv / scan / CSR ----------------
__global__ void count_deg(const int* __restrict__ ei, int* __restrict__ cnt, int E) {
  int e = blockIdx.x * 256 + threadIdx.x;
  if (e < E) atomicAdd(&cnt[ei[E + e]], 1);
}

__global__ void calc_dinv(const int* __restrict__ cnt, float* __restrict__ dinv, int n) {
  int v = blockIdx.x * 256 + threadIdx.x;
  if (v < n) dinv[v] = rsqrtf((float)cnt[v] + 1.0f);  // +1: self-loop
}

// single-block exclusive scan of cnt[n] -> offs[n+1], cursor[n]; 4 elems/thread/iter
__global__ __launch_bounds__(1024) void scan_kernel(const int* __restrict__ cnt,
                                                    int* __restrict__ offs,
                                                    int* __restrict__ cursor, int n) {
  __shared__ int wsum[16];
  __shared__ int woff[16];
  __shared__ int carry_s;
  const int tid = threadIdx.x;
  const int lane = tid & 63, wid = tid >> 6;
  if (tid == 0) carry_s = 0;
  __syncthreads();
  for (int base = 0; base < n; base += 4096) {
    int i0 = base + tid * 4;
    int x[4];
#pragma unroll
    for (int j = 0; j < 4; ++j) x[j] = (i0 + j < n) ? cnt[i0 + j] : 0;
    int tsum = x[0] + x[1] + x[2] + x[3];
    int val = tsum;
#pragma unroll
    for (int d = 1; d < 64; d <<= 1) {
      int t = __shfl_up(val, d, 64);
      if (lane >= d) val += t;
    }
    if (lane == 63) wsum[wid] = val;
    __syncthreads();
    if (wid == 0) {
      int s = (lane < 16) ? wsum[lane] : 0;
      int sv = s;
#pragma unroll
      for (int d = 1; d < 16; d <<= 1) {
        int t = __shfl_up(sv, d, 64);
        if (lane >= d) sv += t;
      }
      if (lane < 16) woff[lane] = sv - s;
    }
    __syncthreads();
    int excl = carry_s + woff[wid] + (val - tsum);
#pragma unroll
    for (int j = 0; j < 4; ++j) {
      if (i0 + j < n) { offs[i0 + j] = excl; cursor[i0 + j] = excl; }
      excl += x[j];
    }
    __syncthreads();
    if (tid == 1023) carry_s = excl;
    __syncthreads();
  }
  if (tid == 0) offs[n] = carry_s;
}

// pack (src<<15) | fp16bits(w): src < 2^17, w > 0 so fp16 sign bit is dropped
__global__ void fill_csr(const int* __restrict__ ei, int* __restrict__ cursor,
                         const float* __restrict__ dinv, unsigned int* __restrict__ csr,
                         int E) {
  int e = blockIdx.x * 256 + threadIdx.x;
  if (e < E) {
    int s = ei[e], d = ei[E + e];
    int p = atomicAdd(&cursor[d], 1);
    float w = dinv[s] * dinv[d];
    __half hw = __float2half(w);
    unsigned int hb = *reinterpret_cast<ushort*>(&hw);
    csr[p] = (((unsigned int)s) << 15) | hb;
  }
}

// ---------------- propagation: one wave per node, one lane per feature ----------------
// Lane l batch-fetches csr[base+l] (256B coalesced per 64 edges), shfl-broadcasts;
// 16 edges in flight (bf16 128B-row gathers), 8 accumulators at reuse distance 8.
template <bool WRITE_BF>
__global__ __launch_bounds__(256) void prop_step(const float* __restrict__ hinf,
                                                 const ushort* __restrict__ hinb,
                                                 float* __restrict__ houtf,
                                                 ushort* __restrict__ houtb,
                                                 const float* __restrict__ h0,
                                                 const int* __restrict__ offs,
                                                 const unsigned int* __restrict__ csr,
                                                 const float* __restrict__ dinv, int n) {
  int gw = (blockIdx.x * 256 + threadIdx.x) >> 6;
  int lane = threadIdx.x & 63;
  if (gw >= n) return;
  float dv = dinv[gw];
  float a[8];
  a[0] = hinf[(size_t)gw * OUT + lane] * dv * dv;  // self loop (exact fp32)
#pragma unroll
  for (int k = 1; k < 8; ++k) a[k] = 0.f;
  int e0 = offs[gw], e1 = offs[gw + 1];
  for (int base = e0; base < e1; base += 64) {
    int rem = e1 - base;
    // padded lanes: u=0 -> src=0, w=+0 (row 0 is valid; contribution is 0)
    unsigned int my = (lane < rem) ? csr[base + lane] : 0u;
    int cnt = rem < 64 ? rem : 64;
    int cnt16 = (cnt + 15) & ~15;
    for (int j = 0; j < cnt16; j += 16) {
      unsigned int u[16];
#pragma unroll
      for (int k = 0; k < 16; ++k) u[k] = (unsigned int)__shfl((int)my, j + k);
      float v[16];
#pragma unroll
      for (int k = 0; k < 16; ++k)
        v[k] = bf2f(hinb[(size_t)(u[k] >> 15) * OUT + lane]);
#pragma unroll
      for (int k = 0; k < 16; ++k) a[k & 7] = fmaf(h15f(u[k]), v[k], a[k & 7]);
    }
  }
  float acc = ((a[0] + a[1]) + (a[2] + a[3])) + ((a[4] + a[5]) + (a[6] + a[7]));
  float o = 0.9f * acc + 0.1f * h0[(size_t)gw * OUT + lane];
  houtf[(size_t)gw * OUT + lane] = o;
  if (WRITE_BF) houtb[(size_t)gw * OUT + lane] = f2bf(o);
}

extern "C" void kernel_launch(void* const* d_in, const int* in_sizes, int n_in,
                              void* d_out, int out_size, void* d_ws, size_t ws_size,
                              hipStream_t stream) {
  const float* X  = (const float*)d_in[0];  // [N,512] f32
  const int*   EI = (const int*)d_in[1];    // [2,E] int32
  const float* W1 = (const float*)d_in[2];  // [512,256] f32
  const float* b1 = (const float*)d_in[3];  // [256] f32
  const float* W2 = (const float*)d_in[4];  // [256,64] f32
  const float* b2 = (const float*)d_in[5];  // [64] f32
  float* out = (float*)d_out;               // [N,64] f32

  const int N = in_sizes[0] / IN;  // 100000
  const int E = in_sizes[1] / 2;   // 3200000

  char* ws = (char*)d_ws;
  size_t o = 0;
  auto alloc = [&](size_t b) {
    char* p = ws + o;
    o = (o + b + 255) & ~(size_t)255;
    return p;
  };
  float*  H0f  = (float*)alloc((size_t)N * OUT * 4);
  ushort* H0b  = (ushort*)alloc((size_t)N * OUT * 2);
  float*  hAf  = (float*)alloc((size_t)N * OUT * 4);
  ushort* hAb  = (ushort*)alloc((size_t)N * OUT * 2);
  float*  hBf  = (float*)alloc((size_t)N * OUT * 4);
  ushort* hBb  = (ushort*)alloc((size_t)N * OUT * 2);
  ushort* h1   = (ushort*)alloc((size_t)N * HID * 2);
  ushort* W1T  = (ushort*)alloc((size_t)IN * HID * 2);
  ushort* W2T  = (ushort*)alloc((size_t)HID * OUT * 2);
  int*    cnt  = (int*)alloc((size_t)N * 4);
  int*    offs = (int*)alloc((size_t)(N + 1) * 4);
  int*    curs = (int*)alloc((size_t)N * 4);
  float*  dinv = (float*)alloc((size_t)N * 4);
  unsigned int* csr = (unsigned int*)alloc((size_t)E * 4);
  (void)ws_size; (void)n_in; (void)out_size;

  transpose_f32_bf16<<<(IN * HID + 255) / 256, 256, 0, stream>>>(W1, W1T, IN, HID);
  transpose_f32_bf16<<<(HID * OUT + 255) / 256, 256, 0, stream>>>(W2, W2T, HID, OUT);

  gemm1<<<dim3((N + 127) / 128, HID / 128), 256, 0, stream>>>(X, W1T, b1, h1, N);
  gemm2<<<(N + 127) / 128, 256, 0, stream>>>(h1, W2T, b2, H0f, H0b, N);

  hipMemsetAsync(cnt, 0, (size_t)N * 4, stream);
  count_deg<<<(E + 255) / 256, 256, 0, stream>>>(EI, cnt, E);
  calc_dinv<<<(N + 255) / 256, 256, 0, stream>>>(cnt, dinv, N);
  scan_kernel<<<1, 1024, 0, stream>>>(cnt, offs, curs, N);
  fill_csr<<<(E + 255) / 256, 256, 0, stream>>>(EI, curs, dinv, csr, E);

  const int pgrid = (N * OUT + 255) / 256;  // one wave per node
  prop_step<true><<<pgrid, 256, 0, stream>>>(H0f, H0b, hAf, hAb, H0f, offs, csr, dinv, N);
  for (int i = 0; i < 4; ++i) {
    prop_step<true><<<pgrid, 256, 0, stream>>>(hAf, hAb, hBf, hBb, H0f, offs, csr, dinv, N);
    prop_step<true><<<pgrid, 256, 0, stream>>>(hBf, hBb, hAf, hAb, H0f, offs, csr, dinv, N);
  }
  prop_step<false><<<pgrid, 256, 0, stream>>>(hAf, hAb, out, nullptr, H0f, offs, csr, dinv, N);
}